// Round 5
// baseline (6551.904 us; speedup 1.0000x reference)
//
#include <hip/hip_runtime.h>
#include <cstddef>
#include <cstdint>

// 2-layer LSTM decoder, B=2048, Z=64, H=256, D=8, T=250. fp32 in/out.
//
// R14: column-split WG pairs -> all 256 CUs, per-CU stream halved.
// R10/R11 (scheduling) and R12/R13 (1024-thr TLP, spill-confounded) all
// nulled; occupancy shows half the chip idle and the 768 KB/step per-WG
// weight stream is batch-independent. So: WG q (q<128) computes hidden
// cols 0..127, WG q+128 cols 128..255 of the same 16 batch rows.
//  - per-WG stream 384 KB/step (16 L0 + 32 L1 tiles/wave), MFMA/cell halved
//  - per-step exchanges: h0' halves (after cell0) and h1 halves (after
//    cell1) via L2 ws buffers + agent-scope flag rendezvous; pair q,q^128
//    lands on the same XCD under %8 round-robin (perf-only assumption).
//    Mutual rendezvous bounds drift -> single-buffer exchange is safe.
//  - partner h1 bf16 for out-proj reconstructed from i8 hi/lo (no extra
//    traffic); flags hipMemsetAsync'd each replay (graph-safe).
//  - NTH=512, 8 waves, VGPR demand ~160 (2 waves/SIMD, no spill regime).
// LDS 44.4 KB. breg[8] ring + cross-phase continuity as R11; pack = R12
// (16 col-group streams, numerically verified in R12/R13).

#define BSZ    2048
#define ZDIM   64
#define HDIM   256
#define DDIM   8
#define TSTEPS 250
#define ROWS   16
#define NWG    256
#define NTH    512            // 8 waves
#define G4     1024
#define WSTR   264            // h1f/woutT row stride (shorts)

#define EXH0_OFF  7094272UL
#define EXH1_OFF  8142848UL
#define FLAGS_OFF 9191424UL

typedef __attribute__((ext_vector_type(4))) int v4i;

__device__ __forceinline__ unsigned short f2bf(float x) {   // RNE f32->bf16
  union { float f; unsigned u; } v; v.f = x;
  unsigned r = v.u + 0x7fff + ((v.u >> 16) & 1);
  return (unsigned short)(r >> 16);
}
__device__ __forceinline__ float bf2f(unsigned short b) {
  union { unsigned u; float f; } v; v.u = (unsigned)b << 16; return v.f;
}
__device__ __forceinline__ float fexp2(float x) { return __builtin_amdgcn_exp2f(x); }
__device__ __forceinline__ float frcp(float x)  { return __builtin_amdgcn_rcpf(x); }
__device__ __forceinline__ float sigm(float x)  { return frcp(1.f + fexp2(-1.44269504f * x)); }
__device__ __forceinline__ float tanh_(float x) { return 2.f * frcp(1.f + fexp2(-2.88539008f * x)) - 1.f; }
__device__ __forceinline__ char q8(float x, float s) {
  float v = fminf(fmaxf(x * s, -127.f), 127.f);
  return (char)(int)__builtin_rintf(v);
}
// h*s split into hi + lo/254 (lo in [-127,127] exactly since 0.5*254=127)
__device__ __forceinline__ void q8pair(float h, float s, char* hi, char* lo) {
  float hs = fminf(fmaxf(h * s, -127.f), 127.f);
  float hq = __builtin_rintf(hs);
  *hi = (char)(int)hq;
  *lo = (char)(int)__builtin_rintf((hs - hq) * 254.f);
}

// ---------------- initial state (mapping verified R1-R8) ----------------
__global__ void init_state(const float* __restrict__ z,
                           const float* __restrict__ Wfh, const float* __restrict__ bfh,
                           const float* __restrict__ Wfc, const float* __restrict__ bfc,
                           char* __restrict__ h0h, char* __restrict__ h0l,
                           char* __restrict__ h1h, char* __restrict__ h1l,
                           float* __restrict__ c0s, float* __restrict__ c1s)
{
  int idx = blockIdx.x * 256 + threadIdx.x;
  int b = idx >> 8;
  int j = idx & 255;
  int col = ((b & 1) << 8) | j;
  const float* z0 = z + (size_t)(b >> 1) * ZDIM;
  const float* z1 = z + (size_t)(1024 + (b >> 1)) * ZDIM;
  float h0 = bfh[col], c0v = bfc[col], h1 = bfh[col], c1v = bfc[col];
  for (int k = 0; k < ZDIM; ++k) {
    float wh = Wfh[k * 512 + col];
    float wc = Wfc[k * 512 + col];
    float a = z0[k], bb = z1[k];
    h0  += a * wh;  c0v += a * wc;
    h1  += bb * wh; c1v += bb * wc;
  }
  char hi, lo;
  q8pair(h0, 31.75f, &hi, &lo); h0h[idx] = hi; h0l[idx] = lo;
  q8pair(h1, 31.75f, &hi, &lo); h1h[idx] = hi; h1l[idx] = lo;
  c0s[idx] = c0v; c1s[idx] = c1v;
}

// ---------------- per-output-column scales (unchanged) ----------------
__global__ void col_scales(const float* __restrict__ Whh0,
                           const float* __restrict__ Wih1, const float* __restrict__ Whh1,
                           float* __restrict__ cs0, float* __restrict__ qs0,
                           float* __restrict__ cs1, float* __restrict__ qs1)
{
  int c = blockIdx.x * 256 + threadIdx.x;   // 0..2047
  if (c < 1024) {
    float m = 0.f;
    for (int k = 0; k < 256; ++k) m = fmaxf(m, fabsf(Whh0[(size_t)k * G4 + c]));
    cs0[c] = m * (1.f / 16129.f);
    qs0[c] = 127.f / m;
  } else {
    c -= 1024;
    float m = 0.f;
    for (int k = 0; k < 256; ++k) m = fmaxf(m, fabsf(Whh1[(size_t)k * G4 + c]));
    for (int k = 0; k < 256; ++k) m = fmaxf(m, fabsf(Wih1[(size_t)k * G4 + c]));
    cs1[c] = m * (1.f / 16129.f);
    qs1[c] = 127.f / m;
  }
}

// ---- i8 weight pack: 16 col-group streams (R12 layout, verified) ----
// Stream sw (0..15): cols sw*16 + l15 per gate. L0: base sw*16 tiles,
// tile r = kc*4 + g (kc<4). L1: base sw*32 tiles, r = kc*4 + g (kc<8).
// Tile interior: lane 16B = k = kc*64 + lq*16 + j, col = g*256 + sw*16 + l15.
__global__ void pack_i8(const float* __restrict__ Whh0,
                        const float* __restrict__ Wih1, const float* __restrict__ Whh1,
                        const float* __restrict__ qs0, const float* __restrict__ qs1,
                        char* __restrict__ p0, char* __restrict__ p1)
{
  int tt   = blockIdx.x * 4 + (threadIdx.x >> 6);   // 0..767
  int lane = threadIdx.x & 63;
  int l15 = lane & 15, lq = lane >> 4;
  union { char c[16]; uint4 u; } v;
  if (tt < 256) {                                   // layer0: sw*16 + kc*4 + g
    int w = tt >> 4, r = tt & 15;
    int kc = r >> 2, g = r & 3;
    int col = g * 256 + w * 16 + l15;
    float q = qs0[col];
    for (int j = 0; j < 16; ++j) {
      int k = kc * 64 + lq * 16 + j;
      v.c[j] = q8(Whh0[(size_t)k * G4 + col], q);
    }
    *(uint4*)(p0 + (size_t)tt * 1024 + lane * 16) = v.u;
  } else {                                          // layer1: sw*32 + kc*4 + g
    int t1 = tt - 256;
    int w = t1 >> 5, r = t1 & 31;
    int kc = r >> 2, g = r & 3;
    int col = g * 256 + w * 16 + l15;
    float q = qs1[col];
    for (int j = 0; j < 16; ++j) {
      int k = kc * 64 + lq * 16 + j;
      float wv = (k < 256) ? Whh1[(size_t)k * G4 + col]
                           : Wih1[(size_t)(k - 256) * G4 + col];
      v.c[j] = q8(wv, q);
    }
    *(uint4*)(p1 + (size_t)t1 * 1024 + lane * 16) = v.u;
  }
}

// ---------------- persistent LSTM kernel (column-split pairs) ----------------
__global__ __launch_bounds__(NTH, 1) void lstm_run(
    const float* __restrict__ target,
    const char* __restrict__ p0, const char* __restrict__ p1,
    const float* __restrict__ bih0, const float* __restrict__ bhh0,
    const float* __restrict__ bih1, const float* __restrict__ bhh1,
    const float* __restrict__ Wih0,
    const float* __restrict__ Wout, const float* __restrict__ bout,
    const char* __restrict__ h0h, const char* __restrict__ h0l,
    const char* __restrict__ h1h, const char* __restrict__ h1l,
    const float* __restrict__ c0s, const float* __restrict__ c1s,
    const float* __restrict__ cs0, const float* __restrict__ cs1,
    char* __restrict__ exh0, char* __restrict__ exh1,
    unsigned* __restrict__ flags,
    float* __restrict__ out)
{
  // double-buffered activation planes: [buf][32 blk-rows * 16], buf = 512 uint4
  __shared__ uint4 X4h[1024];                      // 16 KB
  __shared__ uint4 X4l[1024];                      // 16 KB
  __shared__ unsigned short h1f[16 * WSTR];        // 8.25 KB bf16 h1 (full cols)
  __shared__ unsigned short woutT[8 * WSTR];       // 4.1 KB  (total 44.4 KB)

  const int tid  = threadIdx.x;
  const int w    = tid >> 6;                       // wave 0..7
  const int lane = tid & 63;
  const int l15  = lane & 15;
  const int lq   = lane >> 4;
  const int me   = blockIdx.x;
  const int b0   = (me & 127) * ROWS;
  const int cb   = (me >> 7) * 128;                // own col-half base
  const int cg0  = cb >> 4;                        // own col-group base (0 or 8)
  const int pcg0 = cg0 ^ 8;                        // partner's
  const int pcb  = cb ^ 128;
  const int partner = me ^ 128;
  char* Xch = (char*)X4h;
  char* Xcl = (char*)X4l;
  unsigned* myf = flags + me * 32;
  unsigned* pf  = flags + partner * 32;
  char* exmy0 = exh0 + (size_t)me * 4096;
  char* exmy1 = exh1 + (size_t)me * 4096;
  const char* pex0 = exh0 + (size_t)partner * 4096;
  const char* pex1 = exh1 + (size_t)partner * 4096;

  // ---- one-time staging into buffer 0 (full planes, both halves) ----
  {
    int m = tid & 15, blk = tid >> 4;              // 32 blks x 16 m
    const char* sh = (blk < 16) ? h1h : h0h;
    const char* sl = (blk < 16) ? h1l : h0l;
    int jblk = blk & 15;
    X4h[blk * 16 + m] = *(const uint4*)(sh + (size_t)(b0 + m) * HDIM + jblk * 16);
    X4l[blk * 16 + m] = *(const uint4*)(sl + (size_t)(b0 + m) * HDIM + jblk * 16);
  }
  for (int i = tid; i < HDIM * DDIM; i += NTH) {
    int k = i >> 3, d = i & 7;
    woutT[d * WSTR + k] = f2bf(Wout[i]);
  }

  const int myrow = lq * 4;
  const int jc    = cb + 16 * w + l15;             // own col within gate block
  const int sw    = cg0 + w;                       // weight stream id 0..15
  float c0r[4], c1r[4];
  float bA0[4], bA1[4], csA0[4], csA1[4];          // per gate
  float wx[4][8];                                  // Wih0[d][g*256+jc]
#pragma unroll
  for (int g = 0; g < 4; ++g) {
    int col = g * 256 + jc;
    bA0[g]  = bih0[col] + bhh0[col];
    bA1[g]  = bih1[col] + bhh1[col];
    csA0[g] = cs0[col];
    csA1[g] = cs1[col];
#pragma unroll
    for (int d = 0; d < 8; ++d) wx[g][d] = Wih0[d * G4 + col];
  }
#pragma unroll
  for (int r = 0; r < 4; ++r) {
    c0r[r] = c0s[(size_t)(b0 + myrow + r) * HDIM + jc];
    c1r[r] = c1s[(size_t)(b0 + myrow + r) * HDIM + jc];
  }
  const int opr = tid >> 5, opd = (tid >> 2) & 7, opq = tid & 3;
  const float bo_out = bout[opd];

  // per-lane weight stream bases; tile j at base + j*1024 (linear)
  const char* gp0 = p0 + (size_t)sw * 16384 + lane * 16;
  const char* gp1 = p1 + (size_t)sw * 32768 + lane * 16;

  // 8-deep direct global->VGPR weight stream; rotation carries across phases.
  v4i breg[8];
#pragma unroll
  for (int s = 0; s < 8; ++s)
    breg[s] = *(const v4i*)(gp0 + (size_t)s * 1024);

  __syncthreads();

#pragma unroll 1
  for (int t = 0; t < TSTEPS; ++t) {
    const int xc = (t & 1) << 9;                   // uint4-index base of X_cur
    const int xn = xc ^ 512;                       // X_next

    // ---- teacher-forced input: each thread loads its own 4 rows ----
    float4 xa[4], xb[4];
    if (t > 0) {
      const float* xp = target + (size_t)(b0 + myrow) * (TSTEPS * DDIM)
                               + (size_t)(t - 1) * DDIM;
#pragma unroll
      for (int r = 0; r < 4; ++r) {
        xa[r] = *(const float4*)(xp + (size_t)r * (TSTEPS * DDIM));
        xb[r] = *(const float4*)(xp + (size_t)r * (TSTEPS * DDIM) + 4);
      }
    } else {
#pragma unroll
      for (int r = 0; r < 4; ++r) {
        xa[r] = make_float4(0.f, 0.f, 0.f, 0.f);
        xb[r] = make_float4(0.f, 0.f, 0.f, 0.f);
      }
    }

    const float sc0 = (t <= 1) ? 4.f : 1.f;
    const float sc1 = (t == 0) ? 4.f : 1.f;
    const float wq0 = (t == 0) ? 31.75f : 127.f;

    v4i acch[4], accl[4];
    const v4i zi = {0, 0, 0, 0};

    // ========= layer 0: h0 @ Whh0[:, own cols] (16 tiles) =========
#pragma unroll
    for (int g = 0; g < 4; ++g) { acch[g] = zi; accl[g] = zi; }
    {
      v4i ah, al;
#pragma unroll 8
      for (int j = 0; j < 16; ++j) {
        const int g = j & 3, s = j & 7;
        if (g == 0) {
          int kc = j >> 2;
          int aidx = xc + (16 + kc * 4 + lq) * 16 + l15;
          ah = __builtin_bit_cast(v4i, X4h[aidx]);
          al = __builtin_bit_cast(v4i, X4l[aidx]);
        }
        acch[g] = __builtin_amdgcn_mfma_i32_16x16x64_i8(ah, breg[s], acch[g], 0, 0, 0);
        accl[g] = __builtin_amdgcn_mfma_i32_16x16x64_i8(al, breg[s], accl[g], 0, 0, 0);
        const int jn = j + 8;
        breg[s] = (jn < 16) ? *(const v4i*)(gp0 + (size_t)jn * 1024)
                            : *(const v4i*)(gp1 + (size_t)(jn - 16) * 1024);
      }
    }

    // ---- deferred out-projection for step t-1 (full h1f, stable here) ----
    if (t > 0) {
      float s_ = 0.f;
#pragma unroll
      for (int i = 0; i < 16; ++i) {
        ushort4 hx = *(const ushort4*)&h1f[opr * WSTR + i * 16 + opq * 4];
        ushort4 wv = *(const ushort4*)&woutT[opd * WSTR + i * 16 + opq * 4];
        s_ += bf2f(hx.x) * bf2f(wv.x) + bf2f(hx.y) * bf2f(wv.y)
            + bf2f(hx.z) * bf2f(wv.z) + bf2f(hx.w) * bf2f(wv.w);
      }
      s_ += __shfl_xor(s_, 1);
      s_ += __shfl_xor(s_, 2);
      if (opq == 0)
        out[(size_t)(b0 + opr) * (TSTEPS * DDIM) + (size_t)(t - 1) * DDIM + opd] =
            s_ + bo_out;
    }

    // ---- cell 0: own cols; h0'(t) -> X_next + exchange buffer ----
    {
      float gf[4][4];
#pragma unroll
      for (int g = 0; g < 4; ++g) {
        float cs = csA0[g] * sc0;
#pragma unroll
        for (int r = 0; r < 4; ++r) {
          float d_ = ((float)acch[g][r] + (float)accl[g][r] * (1.f / 254.f)) * cs + bA0[g];
          gf[g][r] = d_
              + xa[r].x * wx[g][0] + xa[r].y * wx[g][1]
              + xa[r].z * wx[g][2] + xa[r].w * wx[g][3]
              + xb[r].x * wx[g][4] + xb[r].y * wx[g][5]
              + xb[r].z * wx[g][6] + xb[r].w * wx[g][7];
        }
      }
#pragma unroll
      for (int r = 0; r < 4; ++r) {
        float iv = sigm(gf[0][r]);
        float fv = sigm(gf[1][r]);
        float gv = tanh_(gf[2][r]);
        float ov = sigm(gf[3][r]);
        c0r[r] = fv * c0r[r] + iv * gv;
        char hi, lo;
        q8pair(ov * tanh_(c0r[r]), wq0, &hi, &lo);
        int off = (xn + (16 + cg0 + w) * 16 + myrow + r) * 16 + l15;
        Xch[off] = hi; Xcl[off] = lo;
        int eoff = w * 256 + (myrow + r) * 16 + l15;
        exmy0[eoff] = hi; exmy0[2048 + eoff] = lo;
      }
    }

    // ---- rendezvous h0 (target 2t+1) ----
    __syncthreads();                               // all stores drained
    if (tid == 0) {
      unsigned tgt = 2 * (unsigned)t + 1;
      __hip_atomic_store(myf, tgt, __ATOMIC_RELEASE, __HIP_MEMORY_SCOPE_AGENT);
      while (__hip_atomic_load(pf, __ATOMIC_ACQUIRE, __HIP_MEMORY_SCOPE_AGENT) < tgt)
        __builtin_amdgcn_s_sleep(2);
    }
    __syncthreads();
    // copy partner h0' half into X_next
    if (tid < 256) {
      int plane = tid >> 7, r7 = tid & 127;
      int pw = r7 >> 4, m = r7 & 15;
      uint4 v = *(const uint4*)(pex0 + plane * 2048 + pw * 256 + m * 16);
      int idx = xn + (16 + pcg0 + pw) * 16 + m;
      if (plane == 0) X4h[idx] = v; else X4l[idx] = v;
    }
    __syncthreads();                               // h0'(t) full & visible

    // ====== layer 1: [h1(t-1) | h0'(t)] @ W1[:, own cols] (32 tiles) ======
#pragma unroll
    for (int g = 0; g < 4; ++g) { acch[g] = zi; accl[g] = zi; }
    {
      v4i ah, al;
#pragma unroll 8
      for (int j = 0; j < 32; ++j) {
        const int g = j & 3, s = j & 7;
        if (g == 0) {
          int kc = j >> 2;                         // 0..3 h1 (cur), 4..7 h0' (next)
          int aidx = (kc < 4) ? (xc + (kc * 4 + lq) * 16 + l15)
                              : (xn + (16 + (kc - 4) * 4 + lq) * 16 + l15);
          ah = __builtin_bit_cast(v4i, X4h[aidx]);
          al = __builtin_bit_cast(v4i, X4l[aidx]);
        }
        acch[g] = __builtin_amdgcn_mfma_i32_16x16x64_i8(ah, breg[s], acch[g], 0, 0, 0);
        accl[g] = __builtin_amdgcn_mfma_i32_16x16x64_i8(al, breg[s], accl[g], 0, 0, 0);
        const int jn = j + 8;
        breg[s] = (jn < 32) ? *(const v4i*)(gp1 + (size_t)jn * 1024)
                            : *(const v4i*)(gp0 + (size_t)(jn - 32) * 1024);
      }
    }

    // ---- cell 1: own cols; h1(t) -> X_next + h1f + exchange buffer ----
#pragma unroll
    for (int r = 0; r < 4; ++r) {
      float di = ((float)acch[0][r] + (float)accl[0][r] * (1.f / 254.f)) * csA1[0] * sc1 + bA1[0];
      float df = ((float)acch[1][r] + (float)accl[1][r] * (1.f / 254.f)) * csA1[1] * sc1 + bA1[1];
      float dg = ((float)acch[2][r] + (float)accl[2][r] * (1.f / 254.f)) * csA1[2] * sc1 + bA1[2];
      float dv = ((float)acch[3][r] + (float)accl[3][r] * (1.f / 254.f)) * csA1[3] * sc1 + bA1[3];
      float iv = sigm(di);
      float fv = sigm(df);
      float gv = tanh_(dg);
      float ov = sigm(dv);
      c1r[r] = fv * c1r[r] + iv * gv;
      float h = ov * tanh_(c1r[r]);
      char hi, lo;
      q8pair(h, 127.f, &hi, &lo);
      int off = (xn + (cg0 + w) * 16 + myrow + r) * 16 + l15;
      Xch[off] = hi; Xcl[off] = lo;
      h1f[(myrow + r) * WSTR + jc] = f2bf(h);
      int eoff = w * 256 + (myrow + r) * 16 + l15;
      exmy1[eoff] = hi; exmy1[2048 + eoff] = lo;
    }

    // ---- rendezvous h1 (target 2t+2) ----
    __syncthreads();
    if (tid == 0) {
      unsigned tgt = 2 * (unsigned)t + 2;
      __hip_atomic_store(myf, tgt, __ATOMIC_RELEASE, __HIP_MEMORY_SCOPE_AGENT);
      while (__hip_atomic_load(pf, __ATOMIC_ACQUIRE, __HIP_MEMORY_SCOPE_AGENT) < tgt)
        __builtin_amdgcn_s_sleep(2);
    }
    __syncthreads();
    // copy partner h1 half into X_next + reconstruct bf16 into h1f
    if (tid < 128) {
      int pw = tid >> 4, m = tid & 15;
      uint4 hv = *(const uint4*)(pex1 + pw * 256 + m * 16);
      uint4 lv = *(const uint4*)(pex1 + 2048 + pw * 256 + m * 16);
      int idx = xn + (pcg0 + pw) * 16 + m;
      X4h[idx] = hv;
      X4l[idx] = lv;
      const signed char* hc = (const signed char*)&hv;
      const signed char* lc = (const signed char*)&lv;
      int colb = pcb + pw * 16;
#pragma unroll
      for (int jj = 0; jj < 16; ++jj) {
        float h = ((float)hc[jj] + (float)lc[jj] * (1.f / 254.f)) * (1.f / 127.f);
        h1f[m * WSTR + colb + jj] = f2bf(h);
      }
    }
    __syncthreads();                               // h1(t)/h1f full & visible
  }

  // ---- epilogue: out-projection for the final step ----
  {
    float s_ = 0.f;
#pragma unroll
    for (int i = 0; i < 16; ++i) {
      ushort4 hx = *(const ushort4*)&h1f[opr * WSTR + i * 16 + opq * 4];
      ushort4 wv = *(const ushort4*)&woutT[opd * WSTR + i * 16 + opq * 4];
      s_ += bf2f(hx.x) * bf2f(wv.x) + bf2f(hx.y) * bf2f(wv.y)
          + bf2f(hx.z) * bf2f(wv.z) + bf2f(hx.w) * bf2f(wv.w);
    }
    s_ += __shfl_xor(s_, 1);
    s_ += __shfl_xor(s_, 2);
    if (opq == 0)
      out[(size_t)(b0 + opr) * (TSTEPS * DDIM) + (size_t)(TSTEPS - 1) * DDIM + opd] =
          s_ + bo_out;
  }
}

extern "C" void kernel_launch(void* const* d_in, const int* in_sizes, int n_in,
                              void* d_out, int out_size, void* d_ws, size_t ws_size,
                              hipStream_t stream) {
  const float* z    = (const float*)d_in[0];
  const float* tgt  = (const float*)d_in[1];
  const float* Wfh  = (const float*)d_in[2];
  const float* bfh  = (const float*)d_in[3];
  const float* Wfc  = (const float*)d_in[4];
  const float* bfc  = (const float*)d_in[5];
  const float* Wih0 = (const float*)d_in[6];
  const float* Whh0 = (const float*)d_in[7];
  const float* bih0 = (const float*)d_in[8];
  const float* bhh0 = (const float*)d_in[9];
  const float* Wih1 = (const float*)d_in[10];
  const float* Whh1 = (const float*)d_in[11];
  const float* bih1 = (const float*)d_in[12];
  const float* bhh1 = (const float*)d_in[13];
  const float* Wout = (const float*)d_in[14];
  const float* bout = (const float*)d_in[15];

  // ws layout (bytes), total ~9.22 MB
  char* ws = (char*)d_ws;
  char*  p0   = ws;                                  // 262,144
  char*  p1   = ws + 262144;                         // 524,288
  char*  h0h  = ws + 786432;                         // 524,288
  char*  h0l  = ws + 1310720;                        // 524,288
  char*  h1h  = ws + 1835008;                        // 524,288
  char*  h1l  = ws + 2359296;                        // 524,288
  float* c0s  = (float*)(ws + 2883584);              // 2,097,152
  float* c1s  = (float*)(ws + 4980736);              // 2,097,152
  float* cs0  = (float*)(ws + 7077888);              // 4,096
  float* qs0  = (float*)(ws + 7081984);              // 4,096
  float* cs1  = (float*)(ws + 7086080);              // 4,096
  float* qs1  = (float*)(ws + 7090176);              // 4,096
  char*  exh0 = ws + EXH0_OFF;                       // 1,048,576
  char*  exh1 = ws + EXH1_OFF;                       // 1,048,576
  unsigned* flags = (unsigned*)(ws + FLAGS_OFF);     // 32,768

  hipMemsetAsync(flags, 0, 32768, stream);
  hipLaunchKernelGGL(init_state, dim3(BSZ * HDIM / 256), dim3(256), 0, stream,
                     z, Wfh, bfh, Wfc, bfc, h0h, h0l, h1h, h1l, c0s, c1s);
  hipLaunchKernelGGL(col_scales, dim3(8), dim3(256), 0, stream,
                     Whh0, Wih1, Whh1, cs0, qs0, cs1, qs1);
  hipLaunchKernelGGL(pack_i8, dim3(192), dim3(256), 0, stream,
                     Whh0, Wih1, Whh1, qs0, qs1, p0, p1);
  hipLaunchKernelGGL(lstm_run, dim3(NWG), dim3(NTH), 0, stream,
                     tgt, p0, p1, bih0, bhh0, bih1, bhh1, Wih0, Wout, bout,
                     h0h, h0l, h1h, h1l, c0s, c1s, cs0, cs1,
                     exh0, exh1, flags, (float*)d_out);
}

// Round 6
// 5669.209 us; speedup vs baseline: 1.1557x; 1.1557x over previous
//
#include <hip/hip_runtime.h>
#include <cstddef>
#include <cstdint>

// 2-layer LSTM decoder, B=2048, Z=64, H=256, D=8, T=250. fp32 in/out.
//
// R15 = R11 shell (128 WG x 8 waves, breg[8] ring, 2 barriers/step) with
// within-wave phase overlap. R11 counters show pipes ~serial (mem ~45% +
// VALU 29% + MFMA 11% ~= 100%): both waves/SIMD are barrier-locked into the
// same phase, so cell VALU never overlaps the weight stream. Fix: weight
// pack re-ordered cc-major (each wave's two 16-col halves = two sequential
// sub-streams) and the cell VALU of half A is interleaved into the fully
// unrolled stream loop of half B, filling vmcnt stall gaps:
//   L0a(16 tiles cc0) || outproj(t-1) pieces
//   L0b(16 tiles cc1) || cell0-cc0 pieces (DEQ g=0..3 at j=1,3,5,7;
//                        ACT r=0..3 at j=9,11,13,15)
//   L1a(32 tiles cc0) pure
//   L1b(32 tiles cc1) || cell1-cc0 row pieces at j=1,9,17,25
//   + short cc1 tails before each barrier.
// Wih0 x-path -> LDS wxa4/wxb4 (R13-verified mapping) frees 64 VGPRs for
// the second accumulator set. h1f single-buffered (reads strictly pre-B,
// writes strictly post-B). State/column mappings identical to R11.
// LDS 76.4 KB. Watch: VGPR <= ~230, WRITE_SIZE ~25 MB (spill signature).

#define BSZ    2048
#define ZDIM   64
#define HDIM   256
#define DDIM   8
#define TSTEPS 250
#define ROWS   16
#define NWG    (BSZ / ROWS)   // 128
#define NTH    512            // 8 waves
#define G4     1024
#define WSTR   264            // h1f/woutT row stride (shorts)

typedef __attribute__((ext_vector_type(4))) int v4i;

__device__ __forceinline__ unsigned short f2bf(float x) {   // RNE f32->bf16
  union { float f; unsigned u; } v; v.f = x;
  unsigned r = v.u + 0x7fff + ((v.u >> 16) & 1);
  return (unsigned short)(r >> 16);
}
__device__ __forceinline__ float bf2f(unsigned short b) {
  union { unsigned u; float f; } v; v.u = (unsigned)b << 16; return v.f;
}
__device__ __forceinline__ float fexp2(float x) { return __builtin_amdgcn_exp2f(x); }
__device__ __forceinline__ float frcp(float x)  { return __builtin_amdgcn_rcpf(x); }
__device__ __forceinline__ float sigm(float x)  { return frcp(1.f + fexp2(-1.44269504f * x)); }
__device__ __forceinline__ float tanh_(float x) { return 2.f * frcp(1.f + fexp2(-2.88539008f * x)) - 1.f; }
__device__ __forceinline__ char q8(float x, float s) {
  float v = fminf(fmaxf(x * s, -127.f), 127.f);
  return (char)(int)__builtin_rintf(v);
}
// h*s split into hi + lo/254 (lo in [-127,127] exactly since 0.5*254=127)
__device__ __forceinline__ void q8pair(float h, float s, char* hi, char* lo) {
  float hs = fminf(fmaxf(h * s, -127.f), 127.f);
  float hq = __builtin_rintf(hs);
  *hi = (char)(int)hq;
  *lo = (char)(int)__builtin_rintf((hs - hq) * 254.f);
}

// ---------------- initial state (mapping verified R1-R8) ----------------
__global__ void init_state(const float* __restrict__ z,
                           const float* __restrict__ Wfh, const float* __restrict__ bfh,
                           const float* __restrict__ Wfc, const float* __restrict__ bfc,
                           char* __restrict__ h0h, char* __restrict__ h0l,
                           char* __restrict__ h1h, char* __restrict__ h1l,
                           float* __restrict__ c0s, float* __restrict__ c1s)
{
  int idx = blockIdx.x * 256 + threadIdx.x;
  int b = idx >> 8;
  int j = idx & 255;
  int col = ((b & 1) << 8) | j;
  const float* z0 = z + (size_t)(b >> 1) * ZDIM;
  const float* z1 = z + (size_t)(1024 + (b >> 1)) * ZDIM;
  float h0 = bfh[col], c0v = bfc[col], h1 = bfh[col], c1v = bfc[col];
  for (int k = 0; k < ZDIM; ++k) {
    float wh = Wfh[k * 512 + col];
    float wc = Wfc[k * 512 + col];
    float a = z0[k], bb = z1[k];
    h0  += a * wh;  c0v += a * wc;
    h1  += bb * wh; c1v += bb * wc;
  }
  char hi, lo;
  q8pair(h0, 31.75f, &hi, &lo); h0h[idx] = hi; h0l[idx] = lo;
  q8pair(h1, 31.75f, &hi, &lo); h1h[idx] = hi; h1l[idx] = lo;
  c0s[idx] = c0v; c1s[idx] = c1v;
}

// ---------------- per-output-column scales (unchanged) ----------------
__global__ void col_scales(const float* __restrict__ Whh0,
                           const float* __restrict__ Wih1, const float* __restrict__ Whh1,
                           float* __restrict__ cs0, float* __restrict__ qs0,
                           float* __restrict__ cs1, float* __restrict__ qs1)
{
  int c = blockIdx.x * 256 + threadIdx.x;   // 0..2047
  if (c < 1024) {
    float m = 0.f;
    for (int k = 0; k < 256; ++k) m = fmaxf(m, fabsf(Whh0[(size_t)k * G4 + c]));
    cs0[c] = m * (1.f / 16129.f);
    qs0[c] = 127.f / m;
  } else {
    c -= 1024;
    float m = 0.f;
    for (int k = 0; k < 256; ++k) m = fmaxf(m, fabsf(Whh1[(size_t)k * G4 + c]));
    for (int k = 0; k < 256; ++k) m = fmaxf(m, fabsf(Wih1[(size_t)k * G4 + c]));
    cs1[c] = m * (1.f / 16129.f);
    qs1[c] = 127.f / m;
  }
}

// ---- i8 weight pack: cc-major per-wave stream (R15) ----
// Wave w (0..7) cols: jc0 = 32w + l15, halves cc=0/1 (+16).
// L0: base w*32 tiles; tile r = cc*16 + kc*4 + g (kc<4).
// L1: base w*64 tiles; tile r = cc*32 + kc*4 + g (kc<8).
// Tile interior (verified R8): lane's 16 B = k = kc*64 + lq*16 + j,
// col = g*256 + 32w + 16cc + l15.
__global__ void pack_i8(const float* __restrict__ Whh0,
                        const float* __restrict__ Wih1, const float* __restrict__ Whh1,
                        const float* __restrict__ qs0, const float* __restrict__ qs1,
                        char* __restrict__ p0, char* __restrict__ p1)
{
  int tt   = blockIdx.x * 4 + (threadIdx.x >> 6);   // 0..767
  int lane = threadIdx.x & 63;
  int l15 = lane & 15, lq = lane >> 4;
  union { char c[16]; uint4 u; } v;
  if (tt < 256) {                                   // layer0
    int w = tt >> 5, r = tt & 31;
    int cc = r >> 4, kc = (r >> 2) & 3, g = r & 3;
    int col = g * 256 + w * 32 + cc * 16 + l15;
    float q = qs0[col];
    for (int j = 0; j < 16; ++j) {
      int k = kc * 64 + lq * 16 + j;
      v.c[j] = q8(Whh0[(size_t)k * G4 + col], q);
    }
    *(uint4*)(p0 + (size_t)tt * 1024 + lane * 16) = v.u;
  } else {                                          // layer1
    int t1 = tt - 256;                              // 0..511
    int w = t1 >> 6, r = t1 & 63;
    int cc = r >> 5, kc = (r >> 2) & 7, g = r & 3;
    int col = g * 256 + w * 32 + cc * 16 + l15;
    float q = qs1[col];
    for (int j = 0; j < 16; ++j) {
      int k = kc * 64 + lq * 16 + j;
      float wv = (k < 256) ? Whh1[(size_t)k * G4 + col]
                           : Wih1[(size_t)(k - 256) * G4 + col];
      v.c[j] = q8(wv, q);
    }
    *(uint4*)(p1 + (size_t)t1 * 1024 + lane * 16) = v.u;
  }
}

// ---------------- persistent LSTM kernel ----------------
__global__ __launch_bounds__(NTH, 1) void lstm_run(
    const float* __restrict__ target,
    const char* __restrict__ p0, const char* __restrict__ p1,
    const float* __restrict__ bih0, const float* __restrict__ bhh0,
    const float* __restrict__ bih1, const float* __restrict__ bhh1,
    const float* __restrict__ Wih0,            // [8,1024] fp32 -> LDS tables
    const float* __restrict__ Wout, const float* __restrict__ bout,
    const char* __restrict__ h0h, const char* __restrict__ h0l,
    const char* __restrict__ h1h, const char* __restrict__ h1l,
    const float* __restrict__ c0s, const float* __restrict__ c1s,
    const float* __restrict__ cs0, const float* __restrict__ cs1,
    float* __restrict__ out)
{
  // double-buffered activation planes: [buf][32 blk-rows * 16], buf = 512 uint4
  __shared__ uint4 X4h[1024];                      // 16 KB
  __shared__ uint4 X4l[1024];                      // 16 KB
  __shared__ unsigned short h1f[16 * WSTR];        // 8.25 KB bf16 h1
  __shared__ unsigned short woutT[8 * WSTR];       // 4.1 KB bf16
  __shared__ float4 wxa4[1024];                    // 16 KB Wih0 d=0..3 per col
  __shared__ float4 wxb4[1024];                    // 16 KB Wih0 d=4..7 per col
                                                   // total ~76.4 KB
  const int tid  = threadIdx.x;
  const int w    = tid >> 6;
  const int lane = tid & 63;
  const int l15  = lane & 15;
  const int lq   = lane >> 4;
  const int b0   = blockIdx.x * ROWS;
  char* Xch = (char*)X4h;
  char* Xcl = (char*)X4l;

  // ---- one-time staging into buffer 0 ----
  {
    int m = tid & 15, blk = tid >> 4;              // 32 blks x 16 m
    const char* sh = (blk < 16) ? h1h : h0h;
    const char* sl = (blk < 16) ? h1l : h0l;
    int jblk = blk & 15;
    X4h[blk * 16 + m] = *(const uint4*)(sh + (size_t)(b0 + m) * HDIM + jblk * 16);
    X4l[blk * 16 + m] = *(const uint4*)(sl + (size_t)(b0 + m) * HDIM + jblk * 16);
  }
  for (int i = tid; i < HDIM * DDIM; i += NTH) {
    int k = i >> 3, d = i & 7;
    woutT[d * WSTR + k] = f2bf(Wout[i]);
  }
  for (int i = tid; i < G4; i += NTH) {
    wxa4[i] = make_float4(Wih0[0 * G4 + i], Wih0[1 * G4 + i],
                          Wih0[2 * G4 + i], Wih0[3 * G4 + i]);
    wxb4[i] = make_float4(Wih0[4 * G4 + i], Wih0[5 * G4 + i],
                          Wih0[6 * G4 + i], Wih0[7 * G4 + i]);
  }

  const int myrow = lq * 4;
  const int jc0   = 32 * w + l15;
  float c0r[2][4], c1r[2][4];
  float bA0[8], bA1[8], csA0[8], csA1[8];          // flat [g*2+cc]
#pragma unroll
  for (int i = 0; i < 8; ++i) {
    int col = (i >> 1) * 256 + jc0 + 16 * (i & 1);
    bA0[i]  = bih0[col] + bhh0[col];
    bA1[i]  = bih1[col] + bhh1[col];
    csA0[i] = cs0[col];
    csA1[i] = cs1[col];
  }
#pragma unroll
  for (int cc = 0; cc < 2; ++cc) {
    int j = jc0 + cc * 16;
#pragma unroll
    for (int r = 0; r < 4; ++r) {
      c0r[cc][r] = c0s[(size_t)(b0 + myrow + r) * HDIM + j];
      c1r[cc][r] = c1s[(size_t)(b0 + myrow + r) * HDIM + j];
    }
  }
  const int opr = tid >> 5, opd = (tid >> 2) & 7, opq = tid & 3;
  const float bo_out = bout[opd];

  // per-lane weight stream bases; tile j at base + j*1024 (linear)
  const char* gp0 = p0 + (size_t)w * 32768 + lane * 16;
  const char* gp1 = p1 + (size_t)w * 65536 + lane * 16;

  // 8-deep direct global->VGPR weight stream; rotation carries across phases.
  v4i breg[8];
#pragma unroll
  for (int s = 0; s < 8; ++s)
    breg[s] = *(const v4i*)(gp0 + (size_t)s * 1024);

  __syncthreads();

#pragma unroll 1
  for (int t = 0; t < TSTEPS; ++t) {
    const int xc = (t & 1) << 9;                   // uint4-index base of X_cur
    const int xn = xc ^ 512;                       // X_next

    // ---- teacher-forced input: each thread loads its own 4 rows ----
    float4 xa[4], xb[4];
    if (t > 0) {
      const float* xp = target + (size_t)(b0 + myrow) * (TSTEPS * DDIM)
                               + (size_t)(t - 1) * DDIM;
#pragma unroll
      for (int r = 0; r < 4; ++r) {
        xa[r] = *(const float4*)(xp + (size_t)r * (TSTEPS * DDIM));
        xb[r] = *(const float4*)(xp + (size_t)r * (TSTEPS * DDIM) + 4);
      }
    } else {
#pragma unroll
      for (int r = 0; r < 4; ++r) {
        xa[r] = make_float4(0.f, 0.f, 0.f, 0.f);
        xb[r] = make_float4(0.f, 0.f, 0.f, 0.f);
      }
    }

    const float sc0 = (t <= 1) ? 4.f : 1.f;
    const float sc1 = (t == 0) ? 4.f : 1.f;
    const float wq0 = (t == 0) ? 31.75f : 127.f;

    v4i pAh[4], pAl[4], pBh[4], pBl[4];
    const v4i zi = {0, 0, 0, 0};
    float gf0[4][4];

    // cell0 filler pieces (constant g/r/cc at every call site)
    auto DEQ0 = [&](const v4i* ph, const v4i* pl, int cc, int g, float (*gf)[4]) {
      int i = g * 2 + cc;
      int col = g * 256 + jc0 + cc * 16;
      float4 wa = wxa4[col];
      float4 wb = wxb4[col];
      float cs = csA0[i] * sc0;
#pragma unroll
      for (int r = 0; r < 4; ++r)
        gf[g][r] = ((float)ph[g][r] + (float)pl[g][r] * (1.f / 254.f)) * cs + bA0[i]
            + xa[r].x * wa.x + xa[r].y * wa.y + xa[r].z * wa.z + xa[r].w * wa.w
            + xb[r].x * wb.x + xb[r].y * wb.y + xb[r].z * wb.z + xb[r].w * wb.w;
    };
    auto ACT0 = [&](int cc, int r, float (*gf)[4]) {
      float iv = sigm(gf[0][r]);
      float fv = sigm(gf[1][r]);
      float gv = tanh_(gf[2][r]);
      float ov = sigm(gf[3][r]);
      c0r[cc][r] = fv * c0r[cc][r] + iv * gv;
      char hi, lo;
      q8pair(ov * tanh_(c0r[cc][r]), wq0, &hi, &lo);
      int off = (xn + (16 + 2 * w + cc) * 16 + myrow + r) * 16 + l15;
      Xch[off] = hi; Xcl[off] = lo;
    };
    // cell1 full-row piece
    auto CELL1R = [&](const v4i* ph, const v4i* pl, int cc, int r) {
      float di = ((float)ph[0][r] + (float)pl[0][r] * (1.f / 254.f)) * csA1[0 + cc] * sc1 + bA1[0 + cc];
      float df = ((float)ph[1][r] + (float)pl[1][r] * (1.f / 254.f)) * csA1[2 + cc] * sc1 + bA1[2 + cc];
      float dg = ((float)ph[2][r] + (float)pl[2][r] * (1.f / 254.f)) * csA1[4 + cc] * sc1 + bA1[4 + cc];
      float dv = ((float)ph[3][r] + (float)pl[3][r] * (1.f / 254.f)) * csA1[6 + cc] * sc1 + bA1[6 + cc];
      float iv = sigm(di);
      float fv = sigm(df);
      float gv = tanh_(dg);
      float ov = sigm(dv);
      c1r[cc][r] = fv * c1r[cc][r] + iv * gv;
      float h = ov * tanh_(c1r[cc][r]);
      char hi, lo;
      q8pair(h, 127.f, &hi, &lo);
      int off = (xn + (2 * w + cc) * 16 + myrow + r) * 16 + l15;
      Xch[off] = hi; Xcl[off] = lo;
      h1f[(myrow + r) * WSTR + jc0 + cc * 16] = f2bf(h);
    };

    // ========= L0a: stream cc0 tiles 0..15 || outproj(t-1) pieces =========
#pragma unroll
    for (int g = 0; g < 4; ++g) { pAh[g] = zi; pAl[g] = zi; }
    {
      v4i ah, al;
      float os_ = 0.f;
#pragma unroll
      for (int j = 0; j < 16; ++j) {
        const int g = j & 3, s = j & 7;
        if (g == 0) {
          int kc = j >> 2;
          int aidx = xc + (16 + kc * 4 + lq) * 16 + l15;
          ah = __builtin_bit_cast(v4i, X4h[aidx]);
          al = __builtin_bit_cast(v4i, X4l[aidx]);
        }
        pAh[g] = __builtin_amdgcn_mfma_i32_16x16x64_i8(ah, breg[s], pAh[g], 0, 0, 0);
        pAl[g] = __builtin_amdgcn_mfma_i32_16x16x64_i8(al, breg[s], pAl[g], 0, 0, 0);
        if (t > 0) {                               // outproj piece j
          ushort4 hx = *(const ushort4*)&h1f[opr * WSTR + j * 16 + opq * 4];
          ushort4 wv = *(const ushort4*)&woutT[opd * WSTR + j * 16 + opq * 4];
          os_ += bf2f(hx.x) * bf2f(wv.x) + bf2f(hx.y) * bf2f(wv.y)
               + bf2f(hx.z) * bf2f(wv.z) + bf2f(hx.w) * bf2f(wv.w);
        }
        const int jn = j + 8;                      // 8..23: always gp0
        breg[s] = *(const v4i*)(gp0 + (size_t)jn * 1024);
      }
      if (t > 0) {
        os_ += __shfl_xor(os_, 1);
        os_ += __shfl_xor(os_, 2);
        if (opq == 0)
          out[(size_t)(b0 + opr) * (TSTEPS * DDIM) + (size_t)(t - 1) * DDIM + opd] =
              os_ + bo_out;
      }
    }

    // ========= L0b: stream cc1 tiles 16..31 || cell0-cc0 pieces =========
#pragma unroll
    for (int g = 0; g < 4; ++g) { pBh[g] = zi; pBl[g] = zi; }
    {
      v4i ah, al;
#pragma unroll
      for (int j = 0; j < 16; ++j) {
        const int g = j & 3, s = j & 7;
        if (g == 0) {
          int kc = j >> 2;
          int aidx = xc + (16 + kc * 4 + lq) * 16 + l15;
          ah = __builtin_bit_cast(v4i, X4h[aidx]);
          al = __builtin_bit_cast(v4i, X4l[aidx]);
        }
        pBh[g] = __builtin_amdgcn_mfma_i32_16x16x64_i8(ah, breg[s], pBh[g], 0, 0, 0);
        pBl[g] = __builtin_amdgcn_mfma_i32_16x16x64_i8(al, breg[s], pBl[g], 0, 0, 0);
        if (j & 1) {                               // fillers: cc0 cell0
          const int p = j >> 1;
          if (p < 4) DEQ0(pAh, pAl, 0, p, gf0);
          else       ACT0(0, p - 4, gf0);
        }
        const int jn = j + 24;                     // 24..39
        breg[s] = (jn < 32) ? *(const v4i*)(gp0 + (size_t)jn * 1024)
                            : *(const v4i*)(gp1 + (size_t)(jn - 32) * 1024);
      }
    }
    // ---- cell0 cc1 tail ----
    {
      float gf1[4][4];
#pragma unroll
      for (int g = 0; g < 4; ++g) DEQ0(pBh, pBl, 1, g, gf1);
#pragma unroll
      for (int r = 0; r < 4; ++r) ACT0(1, r, gf1);
    }
    __syncthreads();   // (B) h0'(t) visible; L1 tiles 0..7 landed

    // ========= L1a: stream L1 cc0 tiles 0..31 (pure) =========
#pragma unroll
    for (int g = 0; g < 4; ++g) { pAh[g] = zi; pAl[g] = zi; }
    {
      v4i ah, al;
#pragma unroll 8
      for (int j = 0; j < 32; ++j) {
        const int g = j & 3, s = j & 7;
        if (g == 0) {
          int kc = j >> 2;                         // 0..3 h1 (cur), 4..7 h0' (next)
          int aidx = (kc < 4) ? (xc + (kc * 4 + lq) * 16 + l15)
                              : (xn + (16 + (kc - 4) * 4 + lq) * 16 + l15);
          ah = __builtin_bit_cast(v4i, X4h[aidx]);
          al = __builtin_bit_cast(v4i, X4l[aidx]);
        }
        pAh[g] = __builtin_amdgcn_mfma_i32_16x16x64_i8(ah, breg[s], pAh[g], 0, 0, 0);
        pAl[g] = __builtin_amdgcn_mfma_i32_16x16x64_i8(al, breg[s], pAl[g], 0, 0, 0);
        const int jn = j + 8;                      // 8..39: always gp1
        breg[s] = *(const v4i*)(gp1 + (size_t)jn * 1024);
      }
    }

    // ========= L1b: stream L1 cc1 tiles 32..63 || cell1-cc0 pieces =========
#pragma unroll
    for (int g = 0; g < 4; ++g) { pBh[g] = zi; pBl[g] = zi; }
    {
      v4i ah, al;
#pragma unroll
      for (int j = 0; j < 32; ++j) {
        const int g = j & 3, s = j & 7;
        if (g == 0) {
          int kc = j >> 2;
          int aidx = (kc < 4) ? (xc + (kc * 4 + lq) * 16 + l15)
                              : (xn + (16 + (kc - 4) * 4 + lq) * 16 + l15);
          ah = __builtin_bit_cast(v4i, X4h[aidx]);
          al = __builtin_bit_cast(v4i, X4l[aidx]);
        }
        pBh[g] = __builtin_amdgcn_mfma_i32_16x16x64_i8(ah, breg[s], pBh[g], 0, 0, 0);
        pBl[g] = __builtin_amdgcn_mfma_i32_16x16x64_i8(al, breg[s], pBl[g], 0, 0, 0);
        if ((j & 7) == 1) CELL1R(pAh, pAl, 0, j >> 3);   // rows 0..3 at j=1,9,17,25
        const int jn = j + 40;                     // 40..71
        breg[s] = (jn < 64) ? *(const v4i*)(gp1 + (size_t)jn * 1024)
                            : *(const v4i*)(gp0 + (size_t)(jn - 64) * 1024);
      }
    }
    // ---- cell1 cc1 tail ----
#pragma unroll
    for (int r = 0; r < 4; ++r) CELL1R(pBh, pBl, 1, r);

    __syncthreads();   // (F) h1(t)/h1f visible; next-step L0 tiles 0..7 landed
  }

  // ---- epilogue: out-projection for the final step ----
  {
    float s_ = 0.f;
#pragma unroll
    for (int i = 0; i < 16; ++i) {
      ushort4 hx = *(const ushort4*)&h1f[opr * WSTR + i * 16 + opq * 4];
      ushort4 wv = *(const ushort4*)&woutT[opd * WSTR + i * 16 + opq * 4];
      s_ += bf2f(hx.x) * bf2f(wv.x) + bf2f(hx.y) * bf2f(wv.y)
          + bf2f(hx.z) * bf2f(wv.z) + bf2f(hx.w) * bf2f(wv.w);
    }
    s_ += __shfl_xor(s_, 1);
    s_ += __shfl_xor(s_, 2);
    if (opq == 0)
      out[(size_t)(b0 + opr) * (TSTEPS * DDIM) + (size_t)(TSTEPS - 1) * DDIM + opd] =
          s_ + bo_out;
  }
}

extern "C" void kernel_launch(void* const* d_in, const int* in_sizes, int n_in,
                              void* d_out, int out_size, void* d_ws, size_t ws_size,
                              hipStream_t stream) {
  const float* z    = (const float*)d_in[0];
  const float* tgt  = (const float*)d_in[1];
  const float* Wfh  = (const float*)d_in[2];
  const float* bfh  = (const float*)d_in[3];
  const float* Wfc  = (const float*)d_in[4];
  const float* bfc  = (const float*)d_in[5];
  const float* Wih0 = (const float*)d_in[6];
  const float* Whh0 = (const float*)d_in[7];
  const float* bih0 = (const float*)d_in[8];
  const float* bhh0 = (const float*)d_in[9];
  const float* Wih1 = (const float*)d_in[10];
  const float* Whh1 = (const float*)d_in[11];
  const float* bih1 = (const float*)d_in[12];
  const float* bhh1 = (const float*)d_in[13];
  const float* Wout = (const float*)d_in[14];
  const float* bout = (const float*)d_in[15];

  // ws layout (bytes), total ~7.09 MB
  char* ws = (char*)d_ws;
  char*  p0   = ws;                                  // 262,144
  char*  p1   = ws + 262144;                         // 524,288
  char*  h0h  = ws + 786432;                         // 524,288
  char*  h0l  = ws + 1310720;                        // 524,288
  char*  h1h  = ws + 1835008;                        // 524,288
  char*  h1l  = ws + 2359296;                        // 524,288
  float* c0s  = (float*)(ws + 2883584);              // 2,097,152
  float* c1s  = (float*)(ws + 4980736);              // 2,097,152
  float* cs0  = (float*)(ws + 7077888);              // 4,096
  float* qs0  = (float*)(ws + 7081984);              // 4,096
  float* cs1  = (float*)(ws + 7086080);              // 4,096
  float* qs1  = (float*)(ws + 7090176);              // 4,096

  hipLaunchKernelGGL(init_state, dim3(BSZ * HDIM / 256), dim3(256), 0, stream,
                     z, Wfh, bfh, Wfc, bfc, h0h, h0l, h1h, h1l, c0s, c1s);
  hipLaunchKernelGGL(col_scales, dim3(8), dim3(256), 0, stream,
                     Whh0, Wih1, Whh1, cs0, qs0, cs1, qs1);
  hipLaunchKernelGGL(pack_i8, dim3(192), dim3(256), 0, stream,
                     Whh0, Wih1, Whh1, qs0, qs1, p0, p1);
  hipLaunchKernelGGL(lstm_run, dim3(NWG), dim3(NTH), 0, stream,
                     tgt, p0, p1, bih0, bhh0, bih1, bhh1, Wih0, Wout, bout,
                     h0h, h0l, h1h, h1l, c0s, c1s, cs0, cs1, (float*)d_out);
}